// Round 2
// baseline (629.150 us; speedup 1.0000x reference)
//
#include <hip/hip_runtime.h>
#include <stdint.h>

// GraphConvLayer: out[n,:] = W[type[n]] @ (A @ x)[n,:]
// N=16384, D=128, T=8.  A is 1 GiB f32 read exactly once -> HBM floor ~163us.
// Strategy: bf16 MFMA GEMM, A staged via registers (f32->bf16 convert) into
// double-buffered LDS, B-fragments loaded directly from LLC-resident g_xT
// (no LDS staging), raw barriers with lgkmcnt-only waits so prefetch loads
// survive across barriers (counted-vmcnt discipline, T3/T4).

#define N_NODES 16384
#define DIM     128
#define NTYPES  8
#define BM      64
#define BK      64
#define NIT     (N_NODES / BK)   // 256

typedef float f32x4 __attribute__((ext_vector_type(4)));
typedef short s16x8 __attribute__((ext_vector_type(8)));

// bf16 staging buffers (module-static device memory; rewritten every call)
__device__ __attribute__((aligned(16))) unsigned short g_xT[DIM * N_NODES];      // [d][n] col-major, 4 MiB
__device__ __attribute__((aligned(16))) unsigned short g_Wb[NTYPES * DIM * DIM]; // [t][o][d], 256 KiB

__device__ __forceinline__ unsigned int f2b(float f) {
    unsigned int u = __float_as_uint(f);
    u += 0x7FFFu + ((u >> 16) & 1u);   // round-to-nearest-even
    return u >> 16;
}
#define BF_LO(u) __uint_as_float((unsigned int)(u) << 16)
#define BF_HI(u) __uint_as_float((unsigned int)(u) & 0xFFFF0000u)

// ---------------- prep kernels ----------------

__global__ void prep_xT(const float* __restrict__ x) {
    int n = blockIdx.x * 256 + threadIdx.x;          // 64 blocks x 256
    const float* row = x + (size_t)n * DIM;
#pragma unroll
    for (int d0 = 0; d0 < DIM; d0 += 4) {
        float4 v = *(const float4*)(row + d0);
        g_xT[(d0 + 0) * N_NODES + n] = (unsigned short)f2b(v.x);
        g_xT[(d0 + 1) * N_NODES + n] = (unsigned short)f2b(v.y);
        g_xT[(d0 + 2) * N_NODES + n] = (unsigned short)f2b(v.z);
        g_xT[(d0 + 3) * N_NODES + n] = (unsigned short)f2b(v.w);
    }
}

__global__ void prep_W(const float* __restrict__ w) {
    int i = (blockIdx.x * 256 + threadIdx.x) * 4;    // 128 blocks x 256
    float4 v = *(const float4*)(w + i);
    ushort4 o;
    o.x = (unsigned short)f2b(v.x); o.y = (unsigned short)f2b(v.y);
    o.z = (unsigned short)f2b(v.z); o.w = (unsigned short)f2b(v.w);
    *(ushort4*)(g_Wb + i) = o;
}

// ---------------- main fused kernel ----------------

#define ASTRIDE 72                          // 64 + 8 pad shorts: row stride 144B -> 2-way-free LDS
#define ABYTES  (BM * ASTRIDE * 2)          // 9216 B per A buffer

// raw barrier: LDS-visibility only; VMEM prefetch stays in flight (never vmcnt(0))
#define BAR() do { asm volatile("s_waitcnt lgkmcnt(0)" ::: "memory"); \
                   __builtin_amdgcn_s_barrier(); } while (0)

__global__ __launch_bounds__(512, 2) void gconv_main(
    const float* __restrict__ adj,
    const int* __restrict__ types,
    float* __restrict__ out)
{
    __shared__ __align__(16) unsigned char lds[64 * 132 * 4]; // 33792 B (A dbuf 18432B; reused as agg f32)
    unsigned short* ab0 = (unsigned short*)lds;
    unsigned short* ab1 = (unsigned short*)(lds + ABYTES);

    const int tid  = threadIdx.x;
    const int w    = tid >> 6;
    const int lane = tid & 63;
    const int m0   = blockIdx.x * BM;

    // wave tiling: rows (w&3)*16, cols (w>>2)*64 (4 n-tiles of 16)
    const int mrow = (w & 3) * 16;
    const int ncol = (w >> 2) * 64;

    f32x4 acc[4] = {};

    // A staging index math (512 threads load 64 rows x 64 f32 per tile)
    const int ar0 = tid >> 4;                 // rows 0..31 (+32 for second load)
    const int ak  = (tid & 15) * 4;           // float4 offset within row
    const float* aBase = adj + (size_t)m0 * N_NODES;
    const float* aPtr0 = aBase + (size_t)ar0 * N_NODES + ak;
    const float* aPtr1 = aBase + (size_t)(ar0 + 32) * N_NODES + ak;

    // B fragment base: column ncol+(lane&15), k-granule lane>>4.
    // 4 lanes (same lane&15) cover one 64B line -> fully coalesced from L2/LLC.
    const unsigned short* bp0 = g_xT + (size_t)(ncol + (lane & 15)) * N_NODES + (lane >> 4) * 8;

    float4 arE0, arE1, arO0, arO1;            // A register stages (even/odd tiles)
    s16x8  bE[8], bO[8];                      // B fragments (even/odd tiles)

    auto LOADA = [&](int t, float4& r0, float4& r1) {
        r0 = *(const float4*)(aPtr0 + t * BK);
        r1 = *(const float4*)(aPtr1 + t * BK);
    };
    auto LOADB = [&](int t, s16x8* b) {
#pragma unroll
        for (int kc = 0; kc < 2; ++kc)
#pragma unroll
            for (int nt = 0; nt < 4; ++nt)
                b[kc * 4 + nt] = *(const s16x8*)(bp0 + (size_t)nt * 16 * N_NODES + t * 64 + kc * 32);
    };
    auto STOREA = [&](unsigned short* As, const float4& r0, const float4& r1) {
        uint2 p;
        p.x = f2b(r0.x) | (f2b(r0.y) << 16);
        p.y = f2b(r0.z) | (f2b(r0.w) << 16);
        *(uint2*)(As + ar0 * ASTRIDE + ak) = p;
        p.x = f2b(r1.x) | (f2b(r1.y) << 16);
        p.y = f2b(r1.z) | (f2b(r1.w) << 16);
        *(uint2*)(As + (ar0 + 32) * ASTRIDE + ak) = p;
    };
    auto COMPUTE = [&](const unsigned short* As, const s16x8* b) {
#pragma unroll
        for (int kc = 0; kc < 2; ++kc) {
            const int kk = kc * 32 + (lane >> 4) * 8;
            s16x8 a = *(const s16x8*)(As + (mrow + (lane & 15)) * ASTRIDE + kk);
#pragma unroll
            for (int nt = 0; nt < 4; ++nt)
                asm("v_mfma_f32_16x16x32_bf16 %0, %1, %2, %0" : "+v"(acc[nt]) : "v"(a), "v"(b[kc * 4 + nt]));
        }
    };

    // ---- prologue: 2 tiles of A + B in flight before first compute ----
    LOADA(0, arE0, arE1);
    LOADA(1, arO0, arO1);
    LOADB(0, bE);
    LOADB(1, bO);
    STOREA(ab0, arE0, arE1);   // compiler inserts counted vmcnt for arE only
    BAR();

    // ---- main loop: 2 tiles per iteration, one barrier per tile ----
    for (int i = 0; i < NIT / 2; ++i) {
        const int t0 = 2 * i;
        // even tile
        if (t0 + 2 < NIT) LOADA(t0 + 2, arE0, arE1);
        COMPUTE(ab0, bE);
        if (t0 + 2 < NIT) LOADB(t0 + 2, bE);
        STOREA(ab1, arO0, arO1);               // A(t0+1), loaded a full phase ago
        BAR();
        // odd tile
        const int t1 = t0 + 1;
        if (t1 + 2 < NIT) LOADA(t1 + 2, arO0, arO1);
        COMPUTE(ab1, bO);
        if (t1 + 2 < NIT) LOADB(t1 + 2, bO);
        if (i + 1 < NIT / 2) { STOREA(ab0, arE0, arE1); BAR(); }
    }
    __syncthreads();   // full drain before reusing LDS as agg

    // ---- epilogue: acc -> LDS agg (f32), then per-row W[type] dots ----
    float* agg = (float*)lds;   // [64][132]
#pragma unroll
    for (int nt = 0; nt < 4; ++nt)
#pragma unroll
        for (int r = 0; r < 4; ++r)
            agg[(mrow + (lane >> 4) * 4 + r) * 132 + ncol + nt * 16 + (lane & 15)] = acc[nt][r];
    __syncthreads();

    const int rbase = w * 8;   // 8 rows per wave
    for (int rr = 0; rr < 8; ++rr) {
        const int rw = rbase + rr;
        const int nn = m0 + rw;
        const int ty = types[nn];                      // wave-uniform
        const unsigned short* Wt = g_Wb + ty * (DIM * DIM);
        const int o0 = lane * 2;
        const float* aggRow = agg + rw * 132;
        float s0 = 0.f, s1 = 0.f;
#pragma unroll
        for (int d0 = 0; d0 < DIM; d0 += 8) {
            float4 ga = *(const float4*)(aggRow + d0);
            float4 gb = *(const float4*)(aggRow + d0 + 4);
            uint4 wa = *(const uint4*)(Wt + o0 * DIM + d0);
            uint4 wb = *(const uint4*)(Wt + (o0 + 1) * DIM + d0);
            s0 += ga.x * BF_LO(wa.x) + ga.y * BF_HI(wa.x) + ga.z * BF_LO(wa.y) + ga.w * BF_HI(wa.y);
            s0 += gb.x * BF_LO(wa.z) + gb.y * BF_HI(wa.z) + gb.z * BF_LO(wa.w) + gb.w * BF_HI(wa.w);
            s1 += ga.x * BF_LO(wb.x) + ga.y * BF_HI(wb.x) + ga.z * BF_LO(wb.y) + ga.w * BF_HI(wb.y);
            s1 += gb.x * BF_LO(wb.z) + gb.y * BF_HI(wb.z) + gb.z * BF_LO(wb.w) + gb.w * BF_HI(wb.w);
        }
        float2 res; res.x = s0; res.y = s1;
        *(float2*)(out + (size_t)nn * DIM + o0) = res;
    }
}

// ---------------- launch ----------------

extern "C" void kernel_launch(void* const* d_in, const int* in_sizes, int n_in,
                              void* d_out, int out_size, void* d_ws, size_t ws_size,
                              hipStream_t stream) {
    const float* x     = (const float*)d_in[0];
    const int*   types = (const int*)d_in[1];
    const float* adj   = (const float*)d_in[2];
    const float* wt    = (const float*)d_in[3];
    float* out = (float*)d_out;

    hipLaunchKernelGGL(prep_xT, dim3(N_NODES / 256), dim3(256), 0, stream, x);
    hipLaunchKernelGGL(prep_W,  dim3((NTYPES * DIM * DIM) / (256 * 4)), dim3(256), 0, stream, wt);
    hipLaunchKernelGGL(gconv_main, dim3(N_NODES / BM), dim3(512), 0, stream, adj, types, out);
}

// Round 3
// 366.057 us; speedup vs baseline: 1.7187x; 1.7187x over previous
//
#include <hip/hip_runtime.h>
#include <stdint.h>

// GraphConvLayer: out[n,:] = W[type[n]] @ (A @ x)[n,:]
// N=16384, D=128, T=8.  A is 1 GiB f32 read exactly once -> HBM floor ~163us.
// bf16 MFMA GEMM. A (f32->bf16 in-register) and xT tiles staged into
// double-buffered LDS; 4-deep named-register global prefetch; lgkm-only
// barriers so VMEM stays in flight (counted vmcnt discipline, T3/T4).
// Round-2 lesson: NO arrays through lambda pointers (scratch spill, rule #20)
// -> everything in named registers via macros.

#define N_NODES 16384
#define DIM     128
#define NTYPES  8
#define BM      64
#define BK      64
#define NIT     (N_NODES / BK)   // 256

typedef float f32x4 __attribute__((ext_vector_type(4)));
typedef short s16x8 __attribute__((ext_vector_type(8)));

__device__ __attribute__((aligned(16))) unsigned short g_xT[DIM * N_NODES];      // [d][n], 4 MiB
__device__ __attribute__((aligned(16))) unsigned short g_Wb[NTYPES * DIM * DIM]; // [t][o][d], 256 KiB

__device__ __forceinline__ unsigned int f2b(float f) {
    unsigned int u = __float_as_uint(f);
    u += 0x7FFFu + ((u >> 16) & 1u);   // round-to-nearest-even
    return u >> 16;
}
#define BF_LO(u) __uint_as_float((unsigned int)(u) << 16)
#define BF_HI(u) __uint_as_float((unsigned int)(u) & 0xFFFF0000u)

// ---------------- prep kernels ----------------

__global__ void prep_xT(const float* __restrict__ x) {
    int n = blockIdx.x * 256 + threadIdx.x;          // 64 blocks x 256
    const float* row = x + (size_t)n * DIM;
#pragma unroll
    for (int d0 = 0; d0 < DIM; d0 += 4) {
        float4 v = *(const float4*)(row + d0);
        g_xT[(d0 + 0) * N_NODES + n] = (unsigned short)f2b(v.x);
        g_xT[(d0 + 1) * N_NODES + n] = (unsigned short)f2b(v.y);
        g_xT[(d0 + 2) * N_NODES + n] = (unsigned short)f2b(v.z);
        g_xT[(d0 + 3) * N_NODES + n] = (unsigned short)f2b(v.w);
    }
}

__global__ void prep_W(const float* __restrict__ w) {
    int i = (blockIdx.x * 256 + threadIdx.x) * 4;    // 128 blocks x 256
    float4 v = *(const float4*)(w + i);
    ushort4 o;
    o.x = (unsigned short)f2b(v.x); o.y = (unsigned short)f2b(v.y);
    o.z = (unsigned short)f2b(v.z); o.w = (unsigned short)f2b(v.w);
    *(ushort4*)(g_Wb + i) = o;
}

// ---------------- main fused kernel ----------------

#define ASTRIDE 72                           // 64 + 8 pad shorts (144 B rows)
#define ABYTES  (BM * ASTRIDE * 2)           // 9216 B per A buffer
#define XBYTES  (DIM * ASTRIDE * 2)          // 18432 B per X buffer

// barrier with LDS-visibility only: VMEM prefetch stays in flight
#define BAR() asm volatile("s_waitcnt lgkmcnt(0)\n\ts_barrier" ::: "memory")

// load tile t of A (2x float4) and X (2x uint4) into named regs
#define LOADG(t, rA0, rA1, rX0, rX1) do {                        \
    rA0 = *(const float4*)(aPtr0 + (size_t)(t) * BK);            \
    rA1 = *(const float4*)(aPtr1 + (size_t)(t) * BK);            \
    rX0 = *(const uint4*)(xPtr0 + (size_t)(t) * BK);             \
    rX1 = *(const uint4*)(xPtr1 + (size_t)(t) * BK);             \
} while (0)

// convert+store one tile's regs into LDS buffers
#define STORE(As_, Xs_, rA0, rA1, rX0, rX1) do {                 \
    uint2 p0, p1;                                                \
    p0.x = f2b(rA0.x) | (f2b(rA0.y) << 16);                      \
    p0.y = f2b(rA0.z) | (f2b(rA0.w) << 16);                      \
    p1.x = f2b(rA1.x) | (f2b(rA1.y) << 16);                      \
    p1.y = f2b(rA1.z) | (f2b(rA1.w) << 16);                      \
    *(uint2*)((As_) + ar0 * ASTRIDE + ak) = p0;                  \
    *(uint2*)((As_) + (ar0 + 32) * ASTRIDE + ak) = p1;           \
    *(uint4*)((Xs_) + xc0 * ASTRIDE + xg * 8) = rX0;             \
    *(uint4*)((Xs_) + (xc0 + 64) * ASTRIDE + xg * 8) = rX1;      \
} while (0)

#define MFMA4(As_, Xs_, kk) do {                                                      \
    s16x8 a_  = *(const s16x8*)((As_) + (mrow + (lane & 15)) * ASTRIDE + (kk));       \
    s16x8 b0_ = *(const s16x8*)((Xs_) + (ncol +  0 + (lane & 15)) * ASTRIDE + (kk));  \
    s16x8 b1_ = *(const s16x8*)((Xs_) + (ncol + 16 + (lane & 15)) * ASTRIDE + (kk));  \
    s16x8 b2_ = *(const s16x8*)((Xs_) + (ncol + 32 + (lane & 15)) * ASTRIDE + (kk));  \
    s16x8 b3_ = *(const s16x8*)((Xs_) + (ncol + 48 + (lane & 15)) * ASTRIDE + (kk));  \
    asm("v_mfma_f32_16x16x32_bf16 %0, %1, %2, %0" : "+v"(acc0) : "v"(a_), "v"(b0_));  \
    asm("v_mfma_f32_16x16x32_bf16 %0, %1, %2, %0" : "+v"(acc1) : "v"(a_), "v"(b1_));  \
    asm("v_mfma_f32_16x16x32_bf16 %0, %1, %2, %0" : "+v"(acc2) : "v"(a_), "v"(b2_));  \
    asm("v_mfma_f32_16x16x32_bf16 %0, %1, %2, %0" : "+v"(acc3) : "v"(a_), "v"(b3_));  \
} while (0)

#define COMPUTE(As_, Xs_) do {           \
    const int kkc = (lane >> 4) * 8;     \
    MFMA4(As_, Xs_, kkc);                \
    MFMA4(As_, Xs_, kkc + 32);           \
} while (0)

__global__ __launch_bounds__(512, 2) void gconv_main(
    const float* __restrict__ adj,
    const int* __restrict__ types,
    float* __restrict__ out)
{
    __shared__ __align__(16) unsigned char lds[2 * ABYTES + 2 * XBYTES]; // 55296 B; reused as agg f32
    unsigned short* As0 = (unsigned short*)lds;
    unsigned short* As1 = As0 + BM * ASTRIDE;
    unsigned short* Xs0 = As0 + 2 * BM * ASTRIDE;
    unsigned short* Xs1 = Xs0 + DIM * ASTRIDE;

    const int tid  = threadIdx.x;
    const int w    = tid >> 6;
    const int lane = tid & 63;
    const int m0   = blockIdx.x * BM;

    const int mrow = (w & 3) * 16;     // wave's 16 output rows
    const int ncol = (w >> 2) * 64;    // wave's 64 output cols

    f32x4 acc0 = {}, acc1 = {}, acc2 = {}, acc3 = {};

    // staging index math (512 threads per tile)
    const int ar0 = tid >> 4;                 // A rows 0..31 (+32)
    const int ak  = (tid & 15) * 4;           // float4 offset in row
    const int xc0 = tid >> 3;                 // X cols (d) 0..63 (+64)
    const int xg  = tid & 7;                  // 16B granule in k
    const float* aBase = adj + (size_t)m0 * N_NODES;
    const float* aPtr0 = aBase + (size_t)ar0 * N_NODES + ak;
    const float* aPtr1 = aBase + (size_t)(ar0 + 32) * N_NODES + ak;
    const unsigned short* xPtr0 = g_xT + (size_t)xc0 * N_NODES + xg * 8;
    const unsigned short* xPtr1 = g_xT + (size_t)(xc0 + 64) * N_NODES + xg * 8;

    // 4 named register parities (NO arrays -> NO scratch)
    float4 aP0a, aP0b, aP1a, aP1b, aP2a, aP2b, aP3a, aP3b;
    uint4  xP0a, xP0b, xP1a, xP1b, xP2a, xP2b, xP3a, xP3b;

    // ---- prologue: 4 tiles in flight, tile 0 staged ----
    LOADG(0, aP0a, aP0b, xP0a, xP0b);
    LOADG(1, aP1a, aP1b, xP1a, xP1b);
    LOADG(2, aP2a, aP2b, xP2a, xP2b);
    LOADG(3, aP3a, aP3b, xP3a, xP3b);
    STORE(As0, Xs0, aP0a, aP0b, xP0a, xP0b);
    BAR();

    // ---- steady state: 4 tiles per iteration, tile t's store is 3 phases
    // after its load issue (~1500 cy latency cover). i=63 peeled (no loads).
    for (int i = 0; i < 63; ++i) {
        const int t0 = 4 * i;
        LOADG(t0 + 4, aP0a, aP0b, xP0a, xP0b);
        COMPUTE(As0, Xs0);
        STORE(As1, Xs1, aP1a, aP1b, xP1a, xP1b);
        BAR();
        LOADG(t0 + 5, aP1a, aP1b, xP1a, xP1b);
        COMPUTE(As1, Xs1);
        STORE(As0, Xs0, aP2a, aP2b, xP2a, xP2b);
        BAR();
        LOADG(t0 + 6, aP2a, aP2b, xP2a, xP2b);
        COMPUTE(As0, Xs0);
        STORE(As1, Xs1, aP3a, aP3b, xP3a, xP3b);
        BAR();
        LOADG(t0 + 7, aP3a, aP3b, xP3a, xP3b);
        COMPUTE(As1, Xs1);
        STORE(As0, Xs0, aP0a, aP0b, xP0a, xP0b);
        BAR();
    }
    // ---- tail: tiles 252..255, no more loads ----
    COMPUTE(As0, Xs0);
    STORE(As1, Xs1, aP1a, aP1b, xP1a, xP1b);
    BAR();
    COMPUTE(As1, Xs1);
    STORE(As0, Xs0, aP2a, aP2b, xP2a, xP2b);
    BAR();
    COMPUTE(As0, Xs0);
    STORE(As1, Xs1, aP3a, aP3b, xP3a, xP3b);
    BAR();
    COMPUTE(As1, Xs1);
    __syncthreads();   // full drain before reusing LDS as agg

    // ---- epilogue: acc -> LDS agg (f32), then per-row W[type] dots ----
    float* agg = (float*)lds;   // [64][132]
#pragma unroll
    for (int r = 0; r < 4; ++r) {
        const int gr = (mrow + (lane >> 4) * 4 + r) * 132 + ncol + (lane & 15);
        agg[gr +  0] = acc0[r];
        agg[gr + 16] = acc1[r];
        agg[gr + 32] = acc2[r];
        agg[gr + 48] = acc3[r];
    }
    __syncthreads();

    const int rbase = w * 8;   // 8 rows per wave
    for (int rr = 0; rr < 8; ++rr) {
        const int rw = rbase + rr;
        const int nn = m0 + rw;
        const int ty = types[nn];                      // wave-uniform
        const unsigned short* Wt = g_Wb + ty * (DIM * DIM);
        const int o0 = lane * 2;
        const float* aggRow = agg + rw * 132;
        float s0 = 0.f, s1 = 0.f;
#pragma unroll
        for (int d0 = 0; d0 < DIM; d0 += 8) {
            float4 ga = *(const float4*)(aggRow + d0);
            float4 gb = *(const float4*)(aggRow + d0 + 4);
            uint4 wa = *(const uint4*)(Wt + o0 * DIM + d0);
            uint4 wb = *(const uint4*)(Wt + (o0 + 1) * DIM + d0);
            s0 += ga.x * BF_LO(wa.x) + ga.y * BF_HI(wa.x) + ga.z * BF_LO(wa.y) + ga.w * BF_HI(wa.y);
            s0 += gb.x * BF_LO(wa.z) + gb.y * BF_HI(wa.z) + gb.z * BF_LO(wa.w) + gb.w * BF_HI(wa.w);
            s1 += ga.x * BF_LO(wb.x) + ga.y * BF_HI(wb.x) + ga.z * BF_LO(wb.y) + ga.w * BF_HI(wb.y);
            s1 += gb.x * BF_LO(wb.z) + gb.y * BF_HI(wb.z) + gb.z * BF_LO(wb.w) + gb.w * BF_HI(wb.w);
        }
        float2 res; res.x = s0; res.y = s1;
        *(float2*)(out + (size_t)nn * DIM + o0) = res;
    }
}

// ---------------- launch ----------------

extern "C" void kernel_launch(void* const* d_in, const int* in_sizes, int n_in,
                              void* d_out, int out_size, void* d_ws, size_t ws_size,
                              hipStream_t stream) {
    const float* x     = (const float*)d_in[0];
    const int*   types = (const int*)d_in[1];
    const float* adj   = (const float*)d_in[2];
    const float* wt    = (const float*)d_in[3];
    float* out = (float*)d_out;

    hipLaunchKernelGGL(prep_xT, dim3(N_NODES / 256), dim3(256), 0, stream, x);
    hipLaunchKernelGGL(prep_W,  dim3((NTYPES * DIM * DIM) / (256 * 4)), dim3(256), 0, stream, wt);
    hipLaunchKernelGGL(gconv_main, dim3(N_NODES / BM), dim3(512), 0, stream, adj, types, out);
}